// Round 11
// baseline (20812.608 us; speedup 1.0000x reference)
//
#include <hip/hip_runtime.h>

// HyperLSTM + MDN decoder — f32 in, f32 out.
// R17 = R16 (bf16x3 MFMA recurrent GEMMs, verified) with K2+K3 fused into one
// kernel via producer->consumer flags: blocks 0-63 compute gate-sum/hh/ch/z
// and release-store flag[b]=t+1; blocks 64-319 run proj epilogue (overlapped),
// acquire-spin on 8 flags, then the einsum+LSTM body. Saves one ~10us kernel
// boundary per step. Fence pattern = R12's correctness-proven one.
#define MM     20
#define LATENT 128
#define IN_DIM 133
#define HD     1024
#define HD4    4096
#define HY     256
#define FF     64
#define NSEQ   128
#define BB     64
#define OUT_DIM 123   // 6*M+3

typedef __attribute__((ext_vector_type(8))) short short8v;   // 8 bf16
typedef __attribute__((ext_vector_type(4))) float f32x4v;

// ---- persistent state / intermediates ----
__device__ float  g_c    [BB * HD];
__device__ float  g_ch   [BB * HY];
__device__ float  g_xT   [NSEQ * 192 * BB];     // strokes^T (pre only)
__device__ float  g_hWh  [8][BB * HD4];         // h@Wh split-K partials (k=128)
__device__ float  g_gH   [8][BB * HD];
__device__ float  g_ghh  [2][BB * HD];
__device__ float  g_z    [BB * 3 * HY];
__device__ float  g_proj [8][BB * 128];
__device__ float  g_xWxA [NSEQ][BB * HD4];      // precomputed x@Wx
__device__ float  g_gxA  [NSEQ][BB * HD];       // precomputed x-part gates
__device__ int    g_flag [BB];                  // producer->consumer step flags
// bf16 hi/lo operand rows (A of MFMA): [b][k]
__device__ unsigned short g_hRowHi [BB * HD],  g_hRowLo [BB * HD];
__device__ unsigned short g_hhRowHi[BB * HY],  g_hhRowLo[BB * HY];
// packed weights, fragment-major: [s][n][lane][8] bf16
__device__ unsigned short pkWhHi[32 * 256 * 512], pkWhLo[32 * 256 * 512];
__device__ unsigned short pkGhHi[32 *  64 * 512], pkGhLo[32 *  64 * 512];
__device__ unsigned short pkHhHi[ 8 *  64 * 512], pkHhLo[ 8 *  64 * 512];
__device__ unsigned short pkPjHi[32 *   8 * 512], pkPjLo[32 *   8 * 512];

__device__ __forceinline__ float sigf(float x) { return 1.0f / (1.0f + expf(-x)); }

__device__ __forceinline__ unsigned short bf16hi(float x) {
    union { float f; unsigned u; } v; v.f = x;
    unsigned r = v.u + 0x7FFFu + ((v.u >> 16) & 1u);
    return (unsigned short)(r >> 16);
}
__device__ __forceinline__ float bf16f(unsigned short h) {
    union { unsigned u; float f; } v; v.u = ((unsigned)h) << 16;
    return v.f;
}
__device__ __forceinline__ void bf16pair(float x, unsigned short* hi, unsigned short* lo) {
    unsigned short h = bf16hi(x);
    *hi = h;
    *lo = bf16hi(x - bf16f(h));
}

__device__ __forceinline__ void gload_lds16(const float* g, float* l) {
    __builtin_amdgcn_global_load_lds(
        (const __attribute__((address_space(1))) void*)g,
        (__attribute__((address_space(3))) void*)l, 16, 0, 0);
}

// ---------------------------------------------------------------------------
// init: s0 = tanh(z @ fc_in_w + fc_in_b); zero flags.  grid 64 x 256
// ---------------------------------------------------------------------------
__global__ __launch_bounds__(256) void init_kernel(
    const float* __restrict__ z, const float* __restrict__ fc_in_w,
    const float* __restrict__ fc_in_b)
{
    int b = blockIdx.x, tid = threadIdx.x;
    if (b == 0 && tid < BB) g_flag[tid] = 0;
    __shared__ float zs[LATENT];
    if (tid < LATENT) zs[tid] = z[b * LATENT + tid];
    __syncthreads();
    for (int j = tid; j < 2560; j += 256) {
        float acc = fc_in_b[j];
        #pragma unroll 4
        for (int k = 0; k < LATENT; k++) acc += zs[k] * fc_in_w[k * 2560 + j];
        float s = tanhf(acc);
        if (j < 1024) {
            bf16pair(s, &g_hRowHi[b * HD + j], &g_hRowLo[b * HD + j]);
        } else if (j < 2048) {
            g_c[b * 1024 + (j - 1024)] = s;
        } else if (j < 2304) {
            int jj = j - 2048;
            bf16pair(s, &g_hhRowHi[b * HY + jj], &g_hhRowLo[b * HY + jj]);
        } else {
            g_ch[b * 256 + (j - 2304)] = s;
        }
    }
}

__global__ __launch_bounds__(256) void xt_kernel(const float* __restrict__ strokes)
{
    int t = blockIdx.x, tid = threadIdx.x;
    for (int i = tid; i < 192 * 64; i += 256) {
        int k = i >> 6, b = i & 63;
        g_xT[t * 192 * 64 + i] =
            (k < IN_DIM) ? strokes[(t * BB + b) * IN_DIM + k] : 0.f;
    }
}

// ---------------------------------------------------------------------------
// pack: weights -> fragment-major bf16 hi/lo (same slot map as A loads).
// ---------------------------------------------------------------------------
__global__ __launch_bounds__(512) void pack_kernel(
    const float* __restrict__ Wh, const float* __restrict__ Wxh_hy,
    const float* __restrict__ Whh_hy, const float* __restrict__ fc_proj_w)
{
    int f = blockIdx.x, tid = threadIdx.x;
    int l = tid >> 3, j = tid & 7;
    int kk = ((l >> 4) << 3) + j, cc = l & 15;
    float val; unsigned short *hi, *lo;
    if (f < 8192) {
        int s = f >> 8, n = f & 255;
        val = Wh[(s * 32 + kk) * HD4 + n * 16 + cc];
        hi = &pkWhHi[f * 512 + tid]; lo = &pkWhLo[f * 512 + tid];
    } else if (f < 10240) {
        int f2 = f - 8192, s = f2 >> 6, n = f2 & 63;
        val = Wxh_hy[(133 + s * 32 + kk) * HD + n * 16 + cc];
        hi = &pkGhHi[f2 * 512 + tid]; lo = &pkGhLo[f2 * 512 + tid];
    } else if (f < 10752) {
        int f2 = f - 10240, s = f2 >> 6, n = f2 & 63;
        val = Whh_hy[(s * 32 + kk) * HD + n * 16 + cc];
        hi = &pkHhHi[f2 * 512 + tid]; lo = &pkHhLo[f2 * 512 + tid];
    } else {
        int f2 = f - 10752, s = f2 >> 3, n = f2 & 7;
        int c = n * 16 + cc;
        val = (c < OUT_DIM) ? fc_proj_w[(s * 32 + kk) * OUT_DIM + c] : 0.f;
        hi = &pkPjHi[f2 * 512 + tid]; lo = &pkPjLo[f2 * 512 + tid];
    }
    bf16pair(val, hi, lo);
}

// ---------------------------------------------------------------------------
// MFMA tile GEMM (bf16x3): 64b x (ntTot-sliced)c. 512 thr = 8 waves.
// ---------------------------------------------------------------------------
template<int NTW>
__device__ __forceinline__ void mfma_gemm(
    const unsigned short* __restrict__ aHi, const unsigned short* __restrict__ aLo,
    int lda,
    const unsigned short* __restrict__ pHi, const unsigned short* __restrict__ pLo,
    int ntTot, int s0, int ns, int n0,
    float* __restrict__ Op, int ldo, int tid)
{
    int w = tid >> 6, l = tid & 63;
    int mt = w & 3, nh = w >> 2;
    int b0 = (mt << 4) + (l & 15);
    int kj = (l >> 4) << 3;
    f32x4v acc[NTW];
    #pragma unroll
    for (int i = 0; i < NTW; i++) acc[i] = (f32x4v){0.f, 0.f, 0.f, 0.f};
    for (int s = 0; s < ns; s++) {
        int sg = s0 + s;
        int koff = (sg << 5) + kj;
        short8v ah = *(const short8v*)(aHi + b0 * lda + koff);
        short8v al = *(const short8v*)(aLo + b0 * lda + koff);
        long fb = ((long)(sg * ntTot + n0 + nh * NTW) << 9) + (l << 3);
        #pragma unroll
        for (int nt = 0; nt < NTW; nt++) {
            short8v bh = *(const short8v*)(pHi + fb + (nt << 9));
            short8v bl = *(const short8v*)(pLo + fb + (nt << 9));
            acc[nt] = __builtin_amdgcn_mfma_f32_16x16x32_bf16(ah, bh, acc[nt], 0, 0, 0);
            acc[nt] = __builtin_amdgcn_mfma_f32_16x16x32_bf16(al, bh, acc[nt], 0, 0, 0);
            acc[nt] = __builtin_amdgcn_mfma_f32_16x16x32_bf16(ah, bl, acc[nt], 0, 0, 0);
        }
    }
    int rb = (mt << 4) + ((l >> 4) << 2);
    int cb = (n0 + nh * NTW) * 16 + (l & 15);
    #pragma unroll
    for (int nt = 0; nt < NTW; nt++) {
        #pragma unroll
        for (int j = 0; j < 4; j++)
            Op[(rb + j) * ldo + cb + (nt << 4)] = acc[nt][j];
    }
}

// ---------------------------------------------------------------------------
// KA: recurrent GEMMs, all MFMA. grid 176 x 512, no LDS.
// ---------------------------------------------------------------------------
__global__ __launch_bounds__(512) void ka_kernel(int t)
{
    int u = blockIdx.x, tid = threadIdx.x;
    if (u < 128) {
        if (t < NSEQ) {
            int ch = u >> 4, ct = u & 15;
            mfma_gemm<8>(g_hRowHi, g_hRowLo, HD, pkWhHi, pkWhLo, 256,
                         ch * 4, 4, ct * 16, g_hWh[ch], HD4, tid);
        }
    } else if (u < 160) {
        if (t < NSEQ) {
            int i = u - 128, ch = i >> 2, ct = i & 3;
            mfma_gemm<8>(g_hRowHi, g_hRowLo, HD, pkGhHi, pkGhLo, 64,
                         ch * 4, 4, ct * 16, g_gH[ch], HD, tid);
        }
    } else if (u < 168) {
        if (t < NSEQ) {
            int i = u - 160, ch = i >> 2, ct = i & 3;
            mfma_gemm<8>(g_hhRowHi, g_hhRowLo, HY, pkHhHi, pkHhLo, 64,
                         ch * 4, 4, ct * 16, g_ghh[ch], HD, tid);
        }
    } else {
        if (t > 0) {
            int ch = u - 168;
            mfma_gemm<4>(g_hRowHi, g_hRowLo, HD, pkPjHi, pkPjLo, 8,
                         ch * 4, 4, 0, g_proj[ch], 128, tid);
        }
    }
}

// ---- f32 VALU 128-col tile GEMM (pre_kernel only) ----
__device__ __forceinline__ void stage128(const float* Wp, int ldw, int wrows,
                                         int co, int pn, float* dst, int tid)
{
    #pragma unroll
    for (int q = 0; q < 2; q++) {
        int s = (q << 9) + tid;
        int r = s >> 5, c4 = s & 31;
        int kr = (pn << 5) + r; if (kr >= wrows) kr = wrows - 1;
        gload_lds16(Wp + kr * ldw + co + (c4 << 2), dst + (s << 2));
    }
}
__device__ __forceinline__ void gemm128(
    const float* AT, const float* Wp, int ldw, int wrows, int co, int np,
    float* Op, int ldo, float* pool, int tid)
{
    int cq = tid & 31, bq = tid >> 5;
    float4 acc0 = {0,0,0,0}, acc1 = {0,0,0,0}, acc2 = {0,0,0,0}, acc3 = {0,0,0,0};
    stage128(Wp, ldw, wrows, co, 0, pool, tid);
    for (int pn = 0; pn < np; pn++) {
        __syncthreads();
        if (pn + 1 < np)
            stage128(Wp, ldw, wrows, co, pn + 1, pool + (((pn + 1) & 1) << 12), tid);
        const float* Ap2 = AT + (pn << 11) + (bq << 2);
        const float* Wcc = pool + ((pn & 1) << 12) + (cq << 2);
        #pragma unroll 8
        for (int k = 0; k < 32; k++) {
            float4 a = *(const float4*)(Ap2 + (k << 6));
            float4 w = *(const float4*)(Wcc + (k << 7));
            acc0.x += a.x*w.x; acc0.y += a.x*w.y; acc0.z += a.x*w.z; acc0.w += a.x*w.w;
            acc1.x += a.y*w.x; acc1.y += a.y*w.y; acc1.z += a.y*w.z; acc1.w += a.y*w.w;
            acc2.x += a.z*w.x; acc2.y += a.z*w.y; acc2.z += a.z*w.z; acc2.w += a.z*w.w;
            acc3.x += a.w*w.x; acc3.y += a.w*w.y; acc3.z += a.w*w.z; acc3.w += a.w*w.w;
        }
    }
    float* op = Op + (bq << 2) * ldo + co + (cq << 2);
    *(float4*)(op)           = acc0;  *(float4*)(op + ldo)     = acc1;
    *(float4*)(op + 2 * ldo) = acc2;  *(float4*)(op + 3 * ldo) = acc3;
}

// ---------------------------------------------------------------------------
// pre: one-time batched x-GEMMs for ALL t. grid 5120 x 512.
// ---------------------------------------------------------------------------
__global__ __launch_bounds__(512, 2) void pre_kernel(
    const float* __restrict__ Wx, const float* __restrict__ Wxh_hy)
{
    __shared__ float pool[8192];
    int u = blockIdx.x, tid = threadIdx.x;
    if (u < 4096) {
        int t = u >> 5, ct = u & 31;
        gemm128(g_xT + t * 192 * 64, Wx, HD4, IN_DIM, ct * 128, 5,
                g_xWxA[t], HD4, pool, tid);
    } else {
        int i = u - 4096, t = i >> 3, ct = i & 7;
        gemm128(g_xT + t * 192 * 64, Wxh_hy, HD, IN_DIM, ct * 128, 5,
                g_gxA[t], HD, pool, tid);
    }
}

// ---------------------------------------------------------------------------
// KB: fused K2+K3. grid 320 x 512.
//  blocks [0,64) producers (b = blk): gate-sum -> hh/ch -> z -> flag[b]=t+1.
//  blocks [64,320) consumers (bg = i>>5, sl = i&31): proj/MDN epilogue for
//  t-1, acquire-spin on 8 flags, then einsum + combine + LSTM update.
// ---------------------------------------------------------------------------
__global__ __launch_bounds__(512) void kb_kernel(
    const float* __restrict__ b_hy,
    const float* __restrict__ Wzx, const float* __restrict__ bzx,
    const float* __restrict__ Wzh, const float* __restrict__ bzh,
    const float* __restrict__ Wzb,
    const float* __restrict__ Dx, const float* __restrict__ Dh,
    const float* __restrict__ Db, const float* __restrict__ b0w,
    const float* __restrict__ fc_proj_b, float* __restrict__ out, int t)
{
    __shared__ float pool[7168];        // 28 KB: producers use 5 KB, consumers 28
    int blk = blockIdx.x, tid = threadIdx.x;

    if (blk < 64) {
        // ===================== producer =====================
        if (t >= NSEQ) return;
        float* gsum = pool;             // 1024
        float* hhB  = pool + 1024;      // 256
        int b = blk, base = b * HD;
        #pragma unroll
        for (int half = 0; half < 2; half++) {
            int j = (half << 9) + tid;
            float a = b_hy[j] + g_gxA[t][base + j];
            #pragma unroll
            for (int c = 0; c < 8; c++) a += g_gH[c][base + j];
            a += g_ghh[0][base + j] + g_ghh[1][base + j];
            gsum[j] = a;
        }
        __syncthreads();
        if (tid < 256) {
            float gi = gsum[tid],       gf = gsum[256 + tid];
            float gg = gsum[512 + tid], go = gsum[768 + tid];
            float ch = g_ch[b * HY + tid];
            ch = sigf(gf) * ch + sigf(gi) * tanhf(gg);
            float hh = sigf(go) * tanhf(ch);
            g_ch[b * HY + tid] = ch;
            bf16pair(hh, &g_hhRowHi[b * HY + tid], &g_hhRowLo[b * HY + tid]);
            hhB[tid] = hh;
        }
        __syncthreads();
        for (int o = tid; o < 768; o += 512) {
            int ten = o >> 8, oo = o & 255;
            const float* Wz = (ten == 0) ? Wzx : (ten == 1) ? Wzh : Wzb;
            float acc = (ten == 0) ? bzx[oo] : (ten == 1) ? bzh[oo] : 0.f;
            #pragma unroll 8
            for (int k = 0; k < HY; k++) acc += hhB[k] * Wz[(k << 8) + oo];
            g_z[b * 768 + o] = acc;
        }
        __syncthreads();                // vmcnt drained: all z stores complete
        if (tid == 0) {
            __threadfence();            // L2 writeback (agent visibility)
            __hip_atomic_store(&g_flag[b], t + 1, __ATOMIC_RELEASE,
                               __HIP_MEMORY_SCOPE_AGENT);
        }
        return;
    }

    // ===================== consumer =====================
    int i = blk - 64, bg = i >> 5, sl = i & 31;
    // proj/MDN epilogue for t-1 FIRST (overlaps producer work)
    if (t > 0 && tid < 31) {
        int it = i * 31 + tid;                     // 0..7935 = 64 b x 124 c
        int b = it / 124, c = it - b * 124;
        int tp = t - 1, base7 = b << 7;
        if (c < 120) {
            float v = fc_proj_b[c];
            #pragma unroll
            for (int q = 0; q < 8; q++) v += g_proj[q][base7 + c];
            int m = c / 6, r = c - m * 6;
            int oidx = tp * (MM * BB) + m * BB + b;
            if      (r == 0) out[oidx]          = 1.0f;   // size-1 softmax
            else if (r == 1) out[163840 + oidx] = v;
            else if (r == 2) out[327680 + oidx] = v;
            else if (r == 3) out[491520 + oidx] = expf(v);
            else if (r == 4) out[655360 + oidx] = expf(v);
            else             out[819200 + oidx] = tanhf(v);
        } else if (c == 120) {                     // pen-state softmax
            float p0 = fc_proj_b[120], p1 = fc_proj_b[121], p2 = fc_proj_b[122];
            #pragma unroll
            for (int q = 0; q < 8; q++) {
                p0 += g_proj[q][base7 + 120];
                p1 += g_proj[q][base7 + 121];
                p2 += g_proj[q][base7 + 122];
            }
            float mx = fmaxf(p0, fmaxf(p1, p2));
            float e0 = expf(p0 - mx), e1 = expf(p1 - mx), e2 = expf(p2 - mx);
            float s = e0 + e1 + e2;
            int ob = 983040 + tp * (BB * 3) + b * 3;
            out[ob + 0] = e0 / s; out[ob + 1] = e1 / s; out[ob + 2] = e2 / s;
        }
    }
    if (t >= NSEQ) return;

    // wait for this bg's 8 producers (wave 0 spins; acquire invalidates caches)
    if (tid < 8) {
        while (__hip_atomic_load(&g_flag[(bg << 3) + tid], __ATOMIC_ACQUIRE,
                                 __HIP_MEMORY_SCOPE_AGENT) < t + 1)
            __builtin_amdgcn_s_sleep(4);
    }
    __syncthreads();

    float* zC   = pool;                 // 6144
    float* preC = pool + 6144;          // 1024
    {
        const float4* src = (const float4*)(g_z + bg * 8 * 768);
        float4* dst = (float4*)zC;
        for (int q = tid; q < 1536; q += 512) dst[q] = src[q];
    }
    __syncthreads();
    int hi0 = sl << 5;
    int hi_l = tid & 31, gq = (tid >> 5) & 3, b4 = tid >> 7;
    int hi = hi0 + hi_l;
    const float* dxp = Dx + gq * 64 * HD + hi;
    const float* dhp = Dh + gq * 64 * HD + hi;
    const float* dbp = Db + gq * 64 * HD + hi;
    const float* z0 = zC + b4 * 768;
    const float* z1 = zC + (b4 + 4) * 768;
    int zo = gq << 6;
    float ax0 = 0.f, ah0 = 0.f, ab0 = 0.f, ax1 = 0.f, ah1 = 0.f, ab1 = 0.f;
    #pragma unroll 4
    for (int f = 0; f < FF; f++) {
        float dx = dxp[f * HD], dh = dhp[f * HD], db = dbp[f * HD];
        ax0 += z0[zo + f] * dx; ah0 += z0[256 + zo + f] * dh;
        ab0 += z0[512 + zo + f] * db;
        ax1 += z1[zo + f] * dx; ah1 += z1[256 + zo + f] * dh;
        ab1 += z1[512 + zo + f] * db;
    }
    int idx = (gq << 10) + hi;
    int b0i = (bg << 3) + b4, b1i = b0i + 4;
    float hw0 = 0.f, hw1 = 0.f;
    #pragma unroll
    for (int q = 0; q < 8; q++) {
        hw0 += g_hWh[q][b0i * HD4 + idx];
        hw1 += g_hWh[q][b1i * HD4 + idx];
    }
    float xw0 = g_xWxA[t][b0i * HD4 + idx], xw1 = g_xWxA[t][b1i * HD4 + idx];
    float bw = b0w[idx];
    float pre0 = ax0 * xw0 + ah0 * hw0 + ab0 + bw;
    float pre1 = ax1 * xw1 + ah1 * hw1 + ab1 + bw;
    preC[((b4 << 2) + gq) * 32 + hi_l]       = pre0;
    preC[(((b4 + 4) << 2) + gq) * 32 + hi_l] = pre1;
    __syncthreads();
    if (tid < 256) {
        int bi = tid >> 5, hl = tid & 31;
        int b8 = (bg << 3) + bi, ha = b8 * HD + hi0 + hl;
        float pi = preC[((bi << 2) + 0) * 32 + hl];
        float pf = preC[((bi << 2) + 1) * 32 + hl];
        float pg = preC[((bi << 2) + 2) * 32 + hl];
        float po = preC[((bi << 2) + 3) * 32 + hl];
        float cv = g_c[ha];
        float nc = sigf(pf) * cv + sigf(pi) * tanhf(pg);
        float nh = sigf(po) * tanhf(nc);
        g_c[ha] = nc;
        bf16pair(nh, &g_hRowHi[ha], &g_hRowLo[ha]);
    }
}

// ---------------------------------------------------------------------------
extern "C" void kernel_launch(void* const* d_in, const int* in_sizes, int n_in,
                              void* d_out, int out_size, void* d_ws, size_t ws_size,
                              hipStream_t stream)
{
    const float* z         = (const float*)d_in[0];
    const float* strokes   = (const float*)d_in[1];
    const float* fc_in_w   = (const float*)d_in[2];
    const float* fc_in_b   = (const float*)d_in[3];
    const float* fc_proj_w = (const float*)d_in[4];
    const float* fc_proj_b = (const float*)d_in[5];
    const float* Wx        = (const float*)d_in[6];
    const float* Wh        = (const float*)d_in[7];
    const float* b0w       = (const float*)d_in[8];
    const float* Wxh_hy    = (const float*)d_in[9];
    const float* Whh_hy    = (const float*)d_in[10];
    const float* b_hy      = (const float*)d_in[11];
    const float* Wzx       = (const float*)d_in[12];
    const float* bzx       = (const float*)d_in[13];
    const float* Wzh       = (const float*)d_in[14];
    const float* bzh       = (const float*)d_in[15];
    const float* Wzb       = (const float*)d_in[16];
    const float* Dx        = (const float*)d_in[17];
    const float* Dh        = (const float*)d_in[18];
    const float* Db        = (const float*)d_in[19];
    (void)d_ws; (void)ws_size; (void)in_sizes; (void)n_in; (void)out_size;
    float* out = (float*)d_out;

    init_kernel<<<64, 256, 0, stream>>>(z, fc_in_w, fc_in_b);
    xt_kernel<<<128, 256, 0, stream>>>(strokes);
    pack_kernel<<<11008, 512, 0, stream>>>(Wh, Wxh_hy, Whh_hy, fc_proj_w);
    pre_kernel<<<5120, 512, 0, stream>>>(Wx, Wxh_hy);
    for (int t = 0; t < NSEQ; t++) {
        ka_kernel<<<176, 512, 0, stream>>>(t);
        kb_kernel<<<320, 512, 0, stream>>>(b_hy, Wzx, bzx, Wzh, bzh, Wzb,
                                           Dx, Dh, Db, b0w, fc_proj_b, out, t);
    }
    // tail: proj of h_127 + its epilogue
    ka_kernel<<<176, 512, 0, stream>>>(NSEQ);
    kb_kernel<<<320, 512, 0, stream>>>(b_hy, Wzx, bzx, Wzh, bzh, Wzb,
                                       Dx, Dh, Db, b0w, fc_proj_b, out, NSEQ);
}

// Round 12
// 8831.542 us; speedup vs baseline: 2.3566x; 2.3566x over previous
//
#include <hip/hip_runtime.h>

// HyperLSTM + MDN decoder — f32 in, f32 out.
// R18 = R16 (bf16x3 MFMA recurrent GEMMs, 5.99ms verified) with K2 merged
// into K3 as KB — ZERO cross-block sync (R12/R17: any in-kernel waiting
// costs 90-120us/step on 8 XCDs). KB grid 64 x 1024: block (bp,half) owns
// 2 b's and a 512-h half; recomputes gate-sum/hh-ch/z block-locally (x2
// redundancy only; z in LDS, no g_z round-trip); ch parity-buffered
// (R15-proven) to kill the cross-half race. 2 launches/step.
#define MM     20
#define LATENT 128
#define IN_DIM 133
#define HD     1024
#define HD4    4096
#define HY     256
#define FF     64
#define NSEQ   128
#define BB     64
#define OUT_DIM 123   // 6*M+3

typedef __attribute__((ext_vector_type(8))) short short8v;   // 8 bf16
typedef __attribute__((ext_vector_type(4))) float f32x4v;

// ---- persistent state / intermediates ----
__device__ float  g_c    [BB * HD];
__device__ float  g_chP  [2][BB * HY];          // parity by step (t&1)
__device__ float  g_xT   [NSEQ * 192 * BB];     // strokes^T (pre only)
__device__ float  g_hWh  [8][BB * HD4];         // h@Wh split-K partials (k=128)
__device__ float  g_gH   [8][BB * HD];
__device__ float  g_ghh  [2][BB * HD];
__device__ float  g_proj [8][BB * 128];
__device__ float  g_xWxA [NSEQ][BB * HD4];      // precomputed x@Wx
__device__ float  g_gxA  [NSEQ][BB * HD];       // precomputed x-part gates
// bf16 hi/lo operand rows (A of MFMA): [b][k]
__device__ unsigned short g_hRowHi [BB * HD],  g_hRowLo [BB * HD];
__device__ unsigned short g_hhRowHi[BB * HY],  g_hhRowLo[BB * HY];
// packed weights, fragment-major: [s][n][lane][8] bf16
__device__ unsigned short pkWhHi[32 * 256 * 512], pkWhLo[32 * 256 * 512];
__device__ unsigned short pkGhHi[32 *  64 * 512], pkGhLo[32 *  64 * 512];
__device__ unsigned short pkHhHi[ 8 *  64 * 512], pkHhLo[ 8 *  64 * 512];
__device__ unsigned short pkPjHi[32 *   8 * 512], pkPjLo[32 *   8 * 512];

__device__ __forceinline__ float sigf(float x) { return 1.0f / (1.0f + expf(-x)); }

__device__ __forceinline__ unsigned short bf16hi(float x) {
    union { float f; unsigned u; } v; v.f = x;
    unsigned r = v.u + 0x7FFFu + ((v.u >> 16) & 1u);
    return (unsigned short)(r >> 16);
}
__device__ __forceinline__ float bf16f(unsigned short h) {
    union { unsigned u; float f; } v; v.u = ((unsigned)h) << 16;
    return v.f;
}
__device__ __forceinline__ void bf16pair(float x, unsigned short* hi, unsigned short* lo) {
    unsigned short h = bf16hi(x);
    *hi = h;
    *lo = bf16hi(x - bf16f(h));
}

__device__ __forceinline__ void gload_lds16(const float* g, float* l) {
    __builtin_amdgcn_global_load_lds(
        (const __attribute__((address_space(1))) void*)g,
        (__attribute__((address_space(3))) void*)l, 16, 0, 0);
}

// ---------------------------------------------------------------------------
// init: s0 = tanh(z @ fc_in_w + fc_in_b).  grid 64 x 256
// ---------------------------------------------------------------------------
__global__ __launch_bounds__(256) void init_kernel(
    const float* __restrict__ z, const float* __restrict__ fc_in_w,
    const float* __restrict__ fc_in_b)
{
    int b = blockIdx.x, tid = threadIdx.x;
    __shared__ float zs[LATENT];
    if (tid < LATENT) zs[tid] = z[b * LATENT + tid];
    __syncthreads();
    for (int j = tid; j < 2560; j += 256) {
        float acc = fc_in_b[j];
        #pragma unroll 4
        for (int k = 0; k < LATENT; k++) acc += zs[k] * fc_in_w[k * 2560 + j];
        float s = tanhf(acc);
        if (j < 1024) {
            bf16pair(s, &g_hRowHi[b * HD + j], &g_hRowLo[b * HD + j]);
        } else if (j < 2048) {
            g_c[b * 1024 + (j - 1024)] = s;
        } else if (j < 2304) {
            int jj = j - 2048;
            bf16pair(s, &g_hhRowHi[b * HY + jj], &g_hhRowLo[b * HY + jj]);
        } else {
            g_chP[0][b * 256 + (j - 2304)] = s;
        }
    }
}

__global__ __launch_bounds__(256) void xt_kernel(const float* __restrict__ strokes)
{
    int t = blockIdx.x, tid = threadIdx.x;
    for (int i = tid; i < 192 * 64; i += 256) {
        int k = i >> 6, b = i & 63;
        g_xT[t * 192 * 64 + i] =
            (k < IN_DIM) ? strokes[(t * BB + b) * IN_DIM + k] : 0.f;
    }
}

// ---------------------------------------------------------------------------
// pack: weights -> fragment-major bf16 hi/lo (same slot map as A loads).
// ---------------------------------------------------------------------------
__global__ __launch_bounds__(512) void pack_kernel(
    const float* __restrict__ Wh, const float* __restrict__ Wxh_hy,
    const float* __restrict__ Whh_hy, const float* __restrict__ fc_proj_w)
{
    int f = blockIdx.x, tid = threadIdx.x;
    int l = tid >> 3, j = tid & 7;
    int kk = ((l >> 4) << 3) + j, cc = l & 15;
    float val; unsigned short *hi, *lo;
    if (f < 8192) {
        int s = f >> 8, n = f & 255;
        val = Wh[(s * 32 + kk) * HD4 + n * 16 + cc];
        hi = &pkWhHi[f * 512 + tid]; lo = &pkWhLo[f * 512 + tid];
    } else if (f < 10240) {
        int f2 = f - 8192, s = f2 >> 6, n = f2 & 63;
        val = Wxh_hy[(133 + s * 32 + kk) * HD + n * 16 + cc];
        hi = &pkGhHi[f2 * 512 + tid]; lo = &pkGhLo[f2 * 512 + tid];
    } else if (f < 10752) {
        int f2 = f - 10240, s = f2 >> 6, n = f2 & 63;
        val = Whh_hy[(s * 32 + kk) * HD + n * 16 + cc];
        hi = &pkHhHi[f2 * 512 + tid]; lo = &pkHhLo[f2 * 512 + tid];
    } else {
        int f2 = f - 10752, s = f2 >> 3, n = f2 & 7;
        int c = n * 16 + cc;
        val = (c < OUT_DIM) ? fc_proj_w[(s * 32 + kk) * OUT_DIM + c] : 0.f;
        hi = &pkPjHi[f2 * 512 + tid]; lo = &pkPjLo[f2 * 512 + tid];
    }
    bf16pair(val, hi, lo);
}

// ---------------------------------------------------------------------------
// MFMA tile GEMM (bf16x3): 64b x (ntTot-sliced)c. 512 thr = 8 waves.
// ---------------------------------------------------------------------------
template<int NTW>
__device__ __forceinline__ void mfma_gemm(
    const unsigned short* __restrict__ aHi, const unsigned short* __restrict__ aLo,
    int lda,
    const unsigned short* __restrict__ pHi, const unsigned short* __restrict__ pLo,
    int ntTot, int s0, int ns, int n0,
    float* __restrict__ Op, int ldo, int tid)
{
    int w = tid >> 6, l = tid & 63;
    int mt = w & 3, nh = w >> 2;
    int b0 = (mt << 4) + (l & 15);
    int kj = (l >> 4) << 3;
    f32x4v acc[NTW];
    #pragma unroll
    for (int i = 0; i < NTW; i++) acc[i] = (f32x4v){0.f, 0.f, 0.f, 0.f};
    for (int s = 0; s < ns; s++) {
        int sg = s0 + s;
        int koff = (sg << 5) + kj;
        short8v ah = *(const short8v*)(aHi + b0 * lda + koff);
        short8v al = *(const short8v*)(aLo + b0 * lda + koff);
        long fb = ((long)(sg * ntTot + n0 + nh * NTW) << 9) + (l << 3);
        #pragma unroll
        for (int nt = 0; nt < NTW; nt++) {
            short8v bh = *(const short8v*)(pHi + fb + (nt << 9));
            short8v bl = *(const short8v*)(pLo + fb + (nt << 9));
            acc[nt] = __builtin_amdgcn_mfma_f32_16x16x32_bf16(ah, bh, acc[nt], 0, 0, 0);
            acc[nt] = __builtin_amdgcn_mfma_f32_16x16x32_bf16(al, bh, acc[nt], 0, 0, 0);
            acc[nt] = __builtin_amdgcn_mfma_f32_16x16x32_bf16(ah, bl, acc[nt], 0, 0, 0);
        }
    }
    int rb = (mt << 4) + ((l >> 4) << 2);
    int cb = (n0 + nh * NTW) * 16 + (l & 15);
    #pragma unroll
    for (int nt = 0; nt < NTW; nt++) {
        #pragma unroll
        for (int j = 0; j < 4; j++)
            Op[(rb + j) * ldo + cb + (nt << 4)] = acc[nt][j];
    }
}

// ---------------------------------------------------------------------------
// KA: recurrent GEMMs, all MFMA. grid 176 x 512, no LDS.
// ---------------------------------------------------------------------------
__global__ __launch_bounds__(512) void ka_kernel(int t)
{
    int u = blockIdx.x, tid = threadIdx.x;
    if (u < 128) {
        if (t < NSEQ) {
            int ch = u >> 4, ct = u & 15;
            mfma_gemm<8>(g_hRowHi, g_hRowLo, HD, pkWhHi, pkWhLo, 256,
                         ch * 4, 4, ct * 16, g_hWh[ch], HD4, tid);
        }
    } else if (u < 160) {
        if (t < NSEQ) {
            int i = u - 128, ch = i >> 2, ct = i & 3;
            mfma_gemm<8>(g_hRowHi, g_hRowLo, HD, pkGhHi, pkGhLo, 64,
                         ch * 4, 4, ct * 16, g_gH[ch], HD, tid);
        }
    } else if (u < 168) {
        if (t < NSEQ) {
            int i = u - 160, ch = i >> 2, ct = i & 3;
            mfma_gemm<8>(g_hhRowHi, g_hhRowLo, HY, pkHhHi, pkHhLo, 64,
                         ch * 4, 4, ct * 16, g_ghh[ch], HD, tid);
        }
    } else {
        if (t > 0) {
            int ch = u - 168;
            mfma_gemm<4>(g_hRowHi, g_hRowLo, HD, pkPjHi, pkPjLo, 8,
                         ch * 4, 4, 0, g_proj[ch], 128, tid);
        }
    }
}

// ---- f32 VALU 128-col tile GEMM (pre_kernel only) ----
__device__ __forceinline__ void stage128(const float* Wp, int ldw, int wrows,
                                         int co, int pn, float* dst, int tid)
{
    #pragma unroll
    for (int q = 0; q < 2; q++) {
        int s = (q << 9) + tid;
        int r = s >> 5, c4 = s & 31;
        int kr = (pn << 5) + r; if (kr >= wrows) kr = wrows - 1;
        gload_lds16(Wp + kr * ldw + co + (c4 << 2), dst + (s << 2));
    }
}
__device__ __forceinline__ void gemm128(
    const float* AT, const float* Wp, int ldw, int wrows, int co, int np,
    float* Op, int ldo, float* pool, int tid)
{
    int cq = tid & 31, bq = tid >> 5;
    float4 acc0 = {0,0,0,0}, acc1 = {0,0,0,0}, acc2 = {0,0,0,0}, acc3 = {0,0,0,0};
    stage128(Wp, ldw, wrows, co, 0, pool, tid);
    for (int pn = 0; pn < np; pn++) {
        __syncthreads();
        if (pn + 1 < np)
            stage128(Wp, ldw, wrows, co, pn + 1, pool + (((pn + 1) & 1) << 12), tid);
        const float* Ap2 = AT + (pn << 11) + (bq << 2);
        const float* Wcc = pool + ((pn & 1) << 12) + (cq << 2);
        #pragma unroll 8
        for (int k = 0; k < 32; k++) {
            float4 a = *(const float4*)(Ap2 + (k << 6));
            float4 w = *(const float4*)(Wcc + (k << 7));
            acc0.x += a.x*w.x; acc0.y += a.x*w.y; acc0.z += a.x*w.z; acc0.w += a.x*w.w;
            acc1.x += a.y*w.x; acc1.y += a.y*w.y; acc1.z += a.y*w.z; acc1.w += a.y*w.w;
            acc2.x += a.z*w.x; acc2.y += a.z*w.y; acc2.z += a.z*w.z; acc2.w += a.z*w.w;
            acc3.x += a.w*w.x; acc3.y += a.w*w.y; acc3.z += a.w*w.z; acc3.w += a.w*w.w;
        }
    }
    float* op = Op + (bq << 2) * ldo + co + (cq << 2);
    *(float4*)(op)           = acc0;  *(float4*)(op + ldo)     = acc1;
    *(float4*)(op + 2 * ldo) = acc2;  *(float4*)(op + 3 * ldo) = acc3;
}

// ---------------------------------------------------------------------------
// pre: one-time batched x-GEMMs for ALL t. grid 5120 x 512.
// ---------------------------------------------------------------------------
__global__ __launch_bounds__(512, 2) void pre_kernel(
    const float* __restrict__ Wx, const float* __restrict__ Wxh_hy)
{
    __shared__ float pool[8192];
    int u = blockIdx.x, tid = threadIdx.x;
    if (u < 4096) {
        int t = u >> 5, ct = u & 31;
        gemm128(g_xT + t * 192 * 64, Wx, HD4, IN_DIM, ct * 128, 5,
                g_xWxA[t], HD4, pool, tid);
    } else {
        int i = u - 4096, t = i >> 3, ct = i & 7;
        gemm128(g_xT + t * 192 * 64, Wxh_hy, HD, IN_DIM, ct * 128, 5,
                g_gxA[t], HD, pool, tid);
    }
}

// ---------------------------------------------------------------------------
// KB: merged K2+K3, no sync. grid 64 x 1024: bp = blk>>1 (2 b's), half = blk&1
// (512-h slice). Phases: epilogue(t-1) -> gate-sum(2b) -> hh/ch (parity;
// half==0 writes state) -> z(2b, LDS) -> einsum+combine -> LSTM update.
// ---------------------------------------------------------------------------
__global__ __launch_bounds__(1024) void kb_kernel(
    const float* __restrict__ b_hy,
    const float* __restrict__ Wzx, const float* __restrict__ bzx,
    const float* __restrict__ Wzh, const float* __restrict__ bzh,
    const float* __restrict__ Wzb,
    const float* __restrict__ Dx, const float* __restrict__ Dh,
    const float* __restrict__ Db, const float* __restrict__ b0w,
    const float* __restrict__ fc_proj_b, float* __restrict__ out, int t)
{
    __shared__ float gsum[2][1024];     // 8 KB
    __shared__ float hhL [2][256];      // 2 KB
    __shared__ float zC  [2][768];      // 6 KB
    __shared__ float preC[2][4][512];   // 16 KB
    int blk = blockIdx.x, tid = threadIdx.x;
    int bp = blk >> 1, half = blk & 1;
    int bA = bp << 1;

    // ---- proj/MDN epilogue for t-1 (block blk -> b = blk, 124 cols) ----
    if (t > 0 && tid < 124) {
        int b = blk, c = tid, tp = t - 1, base7 = b << 7;
        if (c < 120) {
            float v = fc_proj_b[c];
            #pragma unroll
            for (int q = 0; q < 8; q++) v += g_proj[q][base7 + c];
            int m = c / 6, r = c - m * 6;
            int oidx = tp * (MM * BB) + m * BB + b;
            if      (r == 0) out[oidx]          = 1.0f;   // size-1 softmax
            else if (r == 1) out[163840 + oidx] = v;
            else if (r == 2) out[327680 + oidx] = v;
            else if (r == 3) out[491520 + oidx] = expf(v);
            else if (r == 4) out[655360 + oidx] = expf(v);
            else             out[819200 + oidx] = tanhf(v);
        } else if (c == 120) {                   // pen-state softmax
            float p0 = fc_proj_b[120], p1 = fc_proj_b[121], p2 = fc_proj_b[122];
            #pragma unroll
            for (int q = 0; q < 8; q++) {
                p0 += g_proj[q][base7 + 120];
                p1 += g_proj[q][base7 + 121];
                p2 += g_proj[q][base7 + 122];
            }
            float mx = fmaxf(p0, fmaxf(p1, p2));
            float e0 = expf(p0 - mx), e1 = expf(p1 - mx), e2 = expf(p2 - mx);
            float s = e0 + e1 + e2;
            int ob = 983040 + tp * (BB * 3) + b * 3;
            out[ob + 0] = e0 / s; out[ob + 1] = e1 / s; out[ob + 2] = e2 / s;
        }
    }
    if (t >= NSEQ) return;
    int par = t & 1;

    // ---- phase 1: gate-sum for 2 b ----
    #pragma unroll
    for (int b2 = 0; b2 < 2; b2++) {
        int base = (bA + b2) * HD, j = tid;
        float a = b_hy[j] + g_gxA[t][base + j];
        #pragma unroll
        for (int c = 0; c < 8; c++) a += g_gH[c][base + j];
        a += g_ghh[0][base + j] + g_ghh[1][base + j];
        gsum[b2][j] = a;
    }
    __syncthreads();
    // ---- phase 2: hh/ch update (half==0 writes state) ----
    if (tid < 512) {
        int b2 = tid >> 8, e = tid & 255, b = bA + b2;
        float gi = gsum[b2][e],       gf = gsum[b2][256 + e];
        float gg = gsum[b2][512 + e], go = gsum[b2][768 + e];
        float ch = g_chP[par][b * HY + e];
        ch = sigf(gf) * ch + sigf(gi) * tanhf(gg);
        float hh = sigf(go) * tanhf(ch);
        hhL[b2][e] = hh;
        if (half == 0) {
            g_chP[par ^ 1][b * HY + e] = ch;
            bf16pair(hh, &g_hhRowHi[b * HY + e], &g_hhRowLo[b * HY + e]);
        }
    }
    __syncthreads();
    // ---- phase 3: z for 2 b (LDS only) ----
    for (int o = tid; o < 1536; o += 1024) {
        int b2 = (o >= 768) ? 1 : 0;
        int oz = o - (b2 ? 768 : 0);
        int ten = oz >> 8, col = oz & 255;
        const float* Wz = (ten == 0) ? Wzx : (ten == 1) ? Wzh : Wzb;
        float acc = (ten == 0) ? bzx[col] : (ten == 1) ? bzh[col] : 0.f;
        #pragma unroll 8
        for (int k = 0; k < HY; k++) acc += hhL[b2][k] * Wz[(k << 8) + col];
        zC[b2][oz] = acc;
    }
    __syncthreads();
    // ---- phase 4: einsum + combine (float4 over h) ----
    {
        int b2 = tid >> 9, gq = (tid >> 7) & 3, h4 = tid & 127;
        int hi = (half << 9) + (h4 << 2);
        const float* zrow = &zC[b2][gq << 6];
        const float* dxp = Dx + (gq << 6) * HD + hi;
        const float* dhp = Dh + (gq << 6) * HD + hi;
        const float* dbp = Db + (gq << 6) * HD + hi;
        float4 ax = {0,0,0,0}, ah = {0,0,0,0}, ab = {0,0,0,0};
        #pragma unroll 4
        for (int f = 0; f < FF; f++) {
            float zx = zrow[f], zh = zrow[256 + f], zb = zrow[512 + f];
            float4 dx = *(const float4*)(dxp + f * HD);
            float4 dh = *(const float4*)(dhp + f * HD);
            float4 db = *(const float4*)(dbp + f * HD);
            ax.x += zx * dx.x; ax.y += zx * dx.y; ax.z += zx * dx.z; ax.w += zx * dx.w;
            ah.x += zh * dh.x; ah.y += zh * dh.y; ah.z += zh * dh.z; ah.w += zh * dh.w;
            ab.x += zb * db.x; ab.y += zb * db.y; ab.z += zb * db.z; ab.w += zb * db.w;
        }
        int idx = (gq << 10) + hi;
        int b = bA + b2;
        float4 hw = {0,0,0,0};
        #pragma unroll
        for (int q = 0; q < 8; q++) {
            float4 p = *(const float4*)(&g_hWh[q][b * HD4 + idx]);
            hw.x += p.x; hw.y += p.y; hw.z += p.z; hw.w += p.w;
        }
        float4 xw = *(const float4*)(&g_xWxA[t][b * HD4 + idx]);
        float4 bw = *(const float4*)(&b0w[idx]);
        float4 pre;
        pre.x = ax.x * xw.x + ah.x * hw.x + ab.x + bw.x;
        pre.y = ax.y * xw.y + ah.y * hw.y + ab.y + bw.y;
        pre.z = ax.z * xw.z + ah.z * hw.z + ab.z + bw.z;
        pre.w = ax.w * xw.w + ah.w * hw.w + ab.w + bw.w;
        *(float4*)(&preC[b2][gq][h4 << 2]) = pre;
    }
    __syncthreads();
    // ---- phase 5: main LSTM update ----
    {
        int b2 = tid >> 9, hl = tid & 511;
        int b = bA + b2;
        int ha = b * HD + (half << 9) + hl;
        float pi = preC[b2][0][hl], pf = preC[b2][1][hl];
        float pg = preC[b2][2][hl], po = preC[b2][3][hl];
        float cv = g_c[ha];
        float nc = sigf(pf) * cv + sigf(pi) * tanhf(pg);
        float nh = sigf(po) * tanhf(nc);
        g_c[ha] = nc;
        bf16pair(nh, &g_hRowHi[ha], &g_hRowLo[ha]);
    }
}

// ---------------------------------------------------------------------------
extern "C" void kernel_launch(void* const* d_in, const int* in_sizes, int n_in,
                              void* d_out, int out_size, void* d_ws, size_t ws_size,
                              hipStream_t stream)
{
    const float* z         = (const float*)d_in[0];
    const float* strokes   = (const float*)d_in[1];
    const float* fc_in_w   = (const float*)d_in[2];
    const float* fc_in_b   = (const float*)d_in[3];
    const float* fc_proj_w = (const float*)d_in[4];
    const float* fc_proj_b = (const float*)d_in[5];
    const float* Wx        = (const float*)d_in[6];
    const float* Wh        = (const float*)d_in[7];
    const float* b0w       = (const float*)d_in[8];
    const float* Wxh_hy    = (const float*)d_in[9];
    const float* Whh_hy    = (const float*)d_in[10];
    const float* b_hy      = (const float*)d_in[11];
    const float* Wzx       = (const float*)d_in[12];
    const float* bzx       = (const float*)d_in[13];
    const float* Wzh       = (const float*)d_in[14];
    const float* bzh       = (const float*)d_in[15];
    const float* Wzb       = (const float*)d_in[16];
    const float* Dx        = (const float*)d_in[17];
    const float* Dh        = (const float*)d_in[18];
    const float* Db        = (const float*)d_in[19];
    (void)d_ws; (void)ws_size; (void)in_sizes; (void)n_in; (void)out_size;
    float* out = (float*)d_out;

    init_kernel<<<64, 256, 0, stream>>>(z, fc_in_w, fc_in_b);
    xt_kernel<<<128, 256, 0, stream>>>(strokes);
    pack_kernel<<<11008, 512, 0, stream>>>(Wh, Wxh_hy, Whh_hy, fc_proj_w);
    pre_kernel<<<5120, 512, 0, stream>>>(Wx, Wxh_hy);
    for (int t = 0; t < NSEQ; t++) {
        ka_kernel<<<176, 512, 0, stream>>>(t);
        kb_kernel<<<64, 1024, 0, stream>>>(b_hy, Wzx, bzx, Wzh, bzh, Wzb,
                                           Dx, Dh, Db, b0w, fc_proj_b, out, t);
    }
    // tail: proj of h_127 + its epilogue
    ka_kernel<<<176, 512, 0, stream>>>(NSEQ);
    kb_kernel<<<64, 1024, 0, stream>>>(b_hy, Wzx, bzx, Wzh, bzh, Wzb,
                                       Dx, Dh, Db, b0w, fc_proj_b, out, NSEQ);
}